// Round 10
// baseline (158.470 us; speedup 1.0000x reference)
//
#include <hip/hip_runtime.h>
#include <hip/hip_bf16.h>

typedef short bf16x8 __attribute__((ext_vector_type(8)));
typedef float f32x4  __attribute__((ext_vector_type(4)));

__device__ __forceinline__ unsigned short f2bf(float f) {
    union { __hip_bfloat16 b; unsigned short u; } v;
    v.b = __hip_bfloat16(f);          // native RNE cvt (pairs into v_cvt_pk_bf16_f32)
    return v.u;
}

__device__ __forceinline__ f32x4 mfma_bf16(bf16x8 a, bf16x8 b, f32x4 c) {
    return __builtin_amdgcn_mfma_f32_16x16x32_bf16(a, b, c, 0, 0, 0);
}

// pack two f32x4 acc tiles (m-tile 0, m-tile 1) into one bf16 fragment under
// the shared k-bijection pi(g,j) = {4g+j | j<4} u {16+4g+(j-4) | j>=4}
__device__ __forceinline__ bf16x8 pack2(f32x4 lo, f32x4 hi) {
    bf16x8 r;
    r[0] = (short)f2bf(lo[0]); r[1] = (short)f2bf(lo[1]);
    r[2] = (short)f2bf(lo[2]); r[3] = (short)f2bf(lo[3]);
    r[4] = (short)f2bf(hi[0]); r[5] = (short)f2bf(hi[1]);
    r[6] = (short)f2bf(hi[2]); r[7] = (short)f2bf(hi[3]);
    return r;
}

// ---------------- prep: weights -> MFMA-fragment-linear bf16 layout ----------------
// slot s = (((mat*8 + h)*2 + t)*8 + kk)*64 + lane ; each slot = 8 bf16 (16 B).
// content: W[k][n] for n = h*32 + t*16 + (lane&15), k = kk*32 + (lane>>4)*8 + j.
// A wave's fragment load is then ONE contiguous 1 KiB global_load_dwordx4 stream.
__global__ __launch_bounds__(256) void prep_weights(
    const float* __restrict__ wq, const float* __restrict__ wk,
    const float* __restrict__ wv, const float* __restrict__ wo,
    unsigned short* __restrict__ wt)
{
    const int s = blockIdx.x * 256 + threadIdx.x;   // 0..32767
    const int mat  = s >> 13;
    const int h    = (s >> 10) & 7;
    const int t    = (s >> 9) & 1;
    const int kk   = (s >> 6) & 7;
    const int lane = s & 63;
    const int l15  = lane & 15;
    const int g    = lane >> 4;
    const float* src = (mat == 0) ? wq : (mat == 1) ? wk : (mat == 2) ? wv : wo;
    const int n  = h * 32 + t * 16 + l15;
    const int k0 = kk * 32 + g * 8;
    unsigned short* dst = wt + (size_t)s * 8;
#pragma unroll
    for (int j = 0; j < 8; ++j)
        dst[j] = f2bf(src[(k0 + j) * 256 + n]);
}

// ---------------- fused window attention, register-resident attention ----------------
// grid = 1024 (= 16 b * 64 h), block = 512 (8 waves). Each WG owns 64 tokens.
// wave w = head w. SEQUENTIAL projection phases (V per-d-half -> Q -> K) keep the
// accumulator peak at 32 regs and persistent fragments at 48, so unified
// arch+acc fits the 128-reg budget of __launch_bounds__(512,4) -> 2 WG/CU
// (r4 evidence: unified 128 => 41% occupancy; r9 evidence: merged phases =>
// 196 unified => 1 WG/CU). Attention stays register-resident per q-tile.
#define XS_STRIDE 264   // 256 + 8 pad shorts

__global__ __launch_bounds__(512, 4) void win_attn(
    const float* __restrict__ x,
    const unsigned short* __restrict__ wt,   // fragment-linear weights (512 KiB)
    const float* __restrict__ bo,
    float* __restrict__ out)                 // f32 output
{
    __shared__ unsigned short lds[33792];    // 66 KiB
    unsigned short* Xs = lds;                // [64][264]
    unsigned short* Os = lds + 16896;        // [64][264]

    const int tid  = threadIdx.x;
    const int wid  = tid >> 6;               // 0..7 (= head)
    const int lane = tid & 63;
    const int l15  = lane & 15;
    const int g    = lane >> 4;              // 0..3

    const bf16x8* WF = reinterpret_cast<const bf16x8*>(wt);
    // fragment index: (((mat*8 + wid)*2 + t)*8 + kk)*64 + lane
    const int wbase = (wid * 2) * 8 * 64 + lane;
#define WFRAG(mat, t, kk) WF[(mat) * 8192 + wbase + ((t) * 8 + (kk)) * 64]

    const long long base_tok = (long long)blockIdx.x * 64;
    const float* xblk = x + base_tok * 256;

    const f32x4 fz = {0.f, 0.f, 0.f, 0.f};

    // ---- phase 0: stage x row-block as bf16 in LDS ----
#pragma unroll
    for (int i = 0; i < 8; ++i) {
        int p   = tid + i * 512;             // float4 index, 0..4095
        int tok = p >> 6;
        int col = (p & 63) * 4;
        float4 v = reinterpret_cast<const float4*>(xblk)[p];
        ushort4 h;
        h.x = f2bf(v.x); h.y = f2bf(v.y); h.z = f2bf(v.z); h.w = f2bf(v.w);
        *reinterpret_cast<ushort4*>(&Xs[tok * XS_STRIDE + col]) = h;
    }
    __syncthreads();

    // ---- phase 1: V = X Wv, one d-half at a time (acc peak 16) -> PV B-frags ----
    // lane: d = dh*16 + l15, token = mi*16 + 4g + r
    bf16x8 vtf[2][2];                            // [k-half][d-half], 16 regs
#pragma unroll
    for (int dh = 0; dh < 2; ++dh) {
        f32x4 vac[4] = {fz, fz, fz, fz};
#pragma unroll
        for (int kk = 0; kk < 8; ++kk) {
            bf16x8 bv = WFRAG(2, dh, kk);
#pragma unroll
            for (int mi = 0; mi < 4; ++mi) {
                bf16x8 a = *reinterpret_cast<const bf16x8*>(&Xs[(mi * 16 + l15) * XS_STRIDE + kk * 32 + g * 8]);
                vac[mi] = mfma_bf16(a, bv, vac[mi]);
            }
        }
        vtf[0][dh] = pack2(vac[0], vac[1]);
        vtf[1][dh] = pack2(vac[2], vac[3]);
    }

    // ---- phase 2: Q^T = mfma(A = Wq-frag (m=d), B = Xs rows (n=token)) (acc 32) ----
    // lane: token = nt*16 + l15, d = mt*16 + 4g + r
    bf16x8 qtf[4];
    {
        f32x4 qt[2][4] = {{fz, fz, fz, fz}, {fz, fz, fz, fz}};
#pragma unroll
        for (int kk = 0; kk < 8; ++kk) {
            bf16x8 aw[2], bx[4];
            aw[0] = WFRAG(0, 0, kk);
            aw[1] = WFRAG(0, 1, kk);
#pragma unroll
            for (int nt = 0; nt < 4; ++nt)
                bx[nt] = *reinterpret_cast<const bf16x8*>(&Xs[(nt * 16 + l15) * XS_STRIDE + kk * 32 + g * 8]);
#pragma unroll
            for (int mt = 0; mt < 2; ++mt)
#pragma unroll
                for (int nt = 0; nt < 4; ++nt)
                    qt[mt][nt] = mfma_bf16(aw[mt], bx[nt], qt[mt][nt]);
        }
#pragma unroll
        for (int nt = 0; nt < 4; ++nt) qtf[nt] = pack2(qt[0][nt], qt[1][nt]);
    }

    // ---- phase 3: K^T, same structure (acc 32) ----
    bf16x8 ktf[4];
    {
        f32x4 kt[2][4] = {{fz, fz, fz, fz}, {fz, fz, fz, fz}};
#pragma unroll
        for (int kk = 0; kk < 8; ++kk) {
            bf16x8 aw[2], bx[4];
            aw[0] = WFRAG(1, 0, kk);
            aw[1] = WFRAG(1, 1, kk);
#pragma unroll
            for (int nt = 0; nt < 4; ++nt)
                bx[nt] = *reinterpret_cast<const bf16x8*>(&Xs[(nt * 16 + l15) * XS_STRIDE + kk * 32 + g * 8]);
#pragma unroll
            for (int mt = 0; mt < 2; ++mt)
#pragma unroll
                for (int nt = 0; nt < 4; ++nt)
                    kt[mt][nt] = mfma_bf16(aw[mt], bx[nt], kt[mt][nt]);
        }
#pragma unroll
        for (int nt = 0; nt < 4; ++nt) ktf[nt] = pack2(kt[0][nt], kt[1][nt]);
    }

    // ---- phase 4: per q-tile ni: S^T = K Q^T, softmax over k_tok, pa, PV, Os ----
    // st[mi]: lane -> k_tok = mi*16 + 4g + r, q = ni*16 + l15
    constexpr float kC = 0.25501817419392105f;  // (1/sqrt(32)) * log2(e)
#pragma unroll
    for (int ni = 0; ni < 4; ++ni) {
        f32x4 st[4];
#pragma unroll
        for (int mi = 0; mi < 4; ++mi)
            st[mi] = mfma_bf16(ktf[mi], qtf[ni], fz);
        float m = st[0][0];
#pragma unroll
        for (int mi = 0; mi < 4; ++mi)
#pragma unroll
            for (int r = 0; r < 4; ++r) m = fmaxf(m, st[mi][r]);
        m = fmaxf(m, __shfl_xor(m, 16));
        m = fmaxf(m, __shfl_xor(m, 32));
        float sum = 0.f;
#pragma unroll
        for (int mi = 0; mi < 4; ++mi)
#pragma unroll
            for (int r = 0; r < 4; ++r) {
                st[mi][r] = exp2f((st[mi][r] - m) * kC);   // in place
                sum += st[mi][r];
            }
        sum += __shfl_xor(sum, 16);
        sum += __shfl_xor(sum, 32);
        float inv = 1.0f / sum;
        bf16x8 pa[2];                            // P fragment for THIS q-tile only
#pragma unroll
        for (int kk = 0; kk < 2; ++kk) {
            bf16x8 t;
#pragma unroll
            for (int j = 0; j < 4; ++j) {
                t[j]     = (short)f2bf(st[2 * kk][j] * inv);
                t[4 + j] = (short)f2bf(st[2 * kk + 1][j] * inv);
            }
            pa[kk] = t;
        }
        f32x4 oacc[2] = {fz, fz};
#pragma unroll
        for (int kk = 0; kk < 2; ++kk)
#pragma unroll
            for (int dh = 0; dh < 2; ++dh)
                oacc[dh] = mfma_bf16(pa[kk], vtf[kk][dh], oacc[dh]);
#pragma unroll
        for (int dh = 0; dh < 2; ++dh)
#pragma unroll
            for (int r = 0; r < 4; ++r)
                Os[(ni * 16 + g * 4 + r) * XS_STRIDE + wid * 32 + dh * 16 + l15] = f2bf(oacc[dh][r]);
    }
    __syncthreads();

    // ---- phase 5: Y = Os @ Wo + bo, f32 store (acc 32) ----
    {
        f32x4 yacc[4][2] = {{fz, fz}, {fz, fz}, {fz, fz}, {fz, fz}};
#pragma unroll
        for (int kk = 0; kk < 8; ++kk) {
            bf16x8 a[4], b[2];
            b[0] = WFRAG(3, 0, kk);
            b[1] = WFRAG(3, 1, kk);
#pragma unroll
            for (int mi = 0; mi < 4; ++mi)
                a[mi] = *reinterpret_cast<const bf16x8*>(&Os[(mi * 16 + l15) * XS_STRIDE + kk * 32 + g * 8]);
#pragma unroll
            for (int mi = 0; mi < 4; ++mi)
#pragma unroll
                for (int ni = 0; ni < 2; ++ni)
                    yacc[mi][ni] = mfma_bf16(a[mi], b[ni], yacc[mi][ni]);
        }
#pragma unroll
        for (int mi = 0; mi < 4; ++mi) {
#pragma unroll
            for (int ni = 0; ni < 2; ++ni) {
                int col = wid * 32 + ni * 16 + l15;
                float bv = bo[col];
#pragma unroll
                for (int r = 0; r < 4; ++r) {
                    int row = mi * 16 + g * 4 + r;
                    out[(base_tok + row) * 256 + col] = yacc[mi][ni][r] + bv;
                }
            }
        }
    }
#undef WFRAG
}

extern "C" void kernel_launch(void* const* d_in, const int* in_sizes, int n_in,
                              void* d_out, int out_size, void* d_ws, size_t ws_size,
                              hipStream_t stream) {
    const float* x  = (const float*)d_in[0];
    const float* wq = (const float*)d_in[1];
    const float* wk = (const float*)d_in[2];
    const float* wv = (const float*)d_in[3];
    const float* wo = (const float*)d_in[4];
    const float* bo = (const float*)d_in[5];
    unsigned short* wt = (unsigned short*)d_ws;      // 4 * 256*256 bf16 = 512 KiB
    float* out = (float*)d_out;                      // f32 output

    prep_weights<<<128, 256, 0, stream>>>(wq, wk, wv, wo, wt);
    win_attn<<<1024, 512, 0, stream>>>(x, wt, bo, out);
}

// Round 11
// 101.095 us; speedup vs baseline: 1.5675x; 1.5675x over previous
//
#include <hip/hip_runtime.h>
#include <hip/hip_bf16.h>

typedef short bf16x8 __attribute__((ext_vector_type(8)));
typedef float f32x4  __attribute__((ext_vector_type(4)));

__device__ __forceinline__ unsigned short f2bf(float f) {
    union { __hip_bfloat16 b; unsigned short u; } v;
    v.b = __hip_bfloat16(f);          // native RNE cvt (pairs into v_cvt_pk_bf16_f32)
    return v.u;
}

__device__ __forceinline__ f32x4 mfma_bf16(bf16x8 a, bf16x8 b, f32x4 c) {
    return __builtin_amdgcn_mfma_f32_16x16x32_bf16(a, b, c, 0, 0, 0);
}

// async global->LDS 16B: per-lane global src, wave-uniform LDS base (+lane*16 by HW)
__device__ __forceinline__ void gload_lds16(const float* g, float* l) {
    __builtin_amdgcn_global_load_lds(
        (const __attribute__((address_space(1))) unsigned int*)g,
        (__attribute__((address_space(3))) unsigned int*)l, 16, 0, 0);
}

// pack two f32x4 acc tiles (m-tile 0, m-tile 1) into one bf16 fragment under
// the shared k-bijection pi(g,j) = {4g+j | j<4} u {16+4g+(j-4) | j>=4}
__device__ __forceinline__ bf16x8 pack2(f32x4 lo, f32x4 hi) {
    bf16x8 r;
    r[0] = (short)f2bf(lo[0]); r[1] = (short)f2bf(lo[1]);
    r[2] = (short)f2bf(lo[2]); r[3] = (short)f2bf(lo[3]);
    r[4] = (short)f2bf(hi[0]); r[5] = (short)f2bf(hi[1]);
    r[6] = (short)f2bf(hi[2]); r[7] = (short)f2bf(hi[3]);
    return r;
}

// ---------------- prep: weights -> MFMA-fragment-linear bf16 layout ----------------
// slot s = (((mat*8 + h)*2 + t)*8 + kk)*64 + lane ; each slot = 8 bf16 (16 B).
// content: W[k][n] for n = h*32 + t*16 + (lane&15), k = kk*32 + (lane>>4)*8 + j.
__global__ __launch_bounds__(256) void prep_weights(
    const float* __restrict__ wq, const float* __restrict__ wk,
    const float* __restrict__ wv, const float* __restrict__ wo,
    unsigned short* __restrict__ wt)
{
    const int s = blockIdx.x * 256 + threadIdx.x;   // 0..32767
    const int mat  = s >> 13;
    const int h    = (s >> 10) & 7;
    const int t    = (s >> 9) & 1;
    const int kk   = (s >> 6) & 7;
    const int lane = s & 63;
    const int l15  = lane & 15;
    const int g    = lane >> 4;
    const float* src = (mat == 0) ? wq : (mat == 1) ? wk : (mat == 2) ? wv : wo;
    const int n  = h * 32 + t * 16 + l15;
    const int k0 = kk * 32 + g * 8;
    unsigned short* dst = wt + (size_t)s * 8;
#pragma unroll
    for (int j = 0; j < 8; ++j)
        dst[j] = f2bf(src[(k0 + j) * 256 + n]);
}

// ---------------- fused window attention, persistent + async-prefetch ----------------
// grid = 256 persistent WGs (1/CU), 512 thr (8 waves), 4 row-blocks per WG.
// wave w = head w. r9's merged V/Q^T/K^T kk-loop + register-resident attention.
// x for block it+1 is DMA'd (global_load_lds) into a 64 KiB f32 LDS buffer while
// block it computes -> x-stage latency fully hidden. (512,2): no spill (r6-r10).
#define XS_STRIDE 264   // 256 + 8 pad shorts

__global__ __launch_bounds__(512, 2) void win_attn(
    const float* __restrict__ x,
    const unsigned short* __restrict__ wt,   // fragment-linear weights (512 KiB)
    const float* __restrict__ bo,
    float* __restrict__ out)                 // f32 output
{
    __shared__ unsigned short lds16[33792];  // 66 KiB: Xs + Os
    __shared__ float XfF[16384];             // 64 KiB: raw f32 x block (prefetch dst)
    unsigned short* Xs = lds16;              // [64][264] bf16
    unsigned short* Os = lds16 + 16896;      // [64][264] bf16

    const int tid  = threadIdx.x;
    const int wid  = tid >> 6;               // 0..7 (= head)
    const int lane = tid & 63;
    const int l15  = lane & 15;
    const int g    = lane >> 4;              // 0..3

    const bf16x8* WF = reinterpret_cast<const bf16x8*>(wt);
    // fragment index: (((mat*8 + wid)*2 + t)*8 + kk)*64 + lane
    const int wbase = (wid * 2) * 8 * 64 + lane;
#define WFRAG(mat, t, kk) WF[(mat) * 8192 + wbase + ((t) * 8 + (kk)) * 64]

    const f32x4 fz = {0.f, 0.f, 0.f, 0.f};
    constexpr float kC = 0.25501817419392105f;  // (1/sqrt(32)) * log2(e)

    // ---- prologue: issue async copy of x block for it=0 (wave w moves rows 8w..8w+7)
    {
        const float* src = x + (size_t)blockIdx.x * 16384;
#pragma unroll
        for (int i = 0; i < 8; ++i) {
            int chunk = wid * 8 + i;                       // one 256-float row
            gload_lds16(src + chunk * 256 + lane * 4, XfF + chunk * 256);
        }
    }

    for (int it = 0; it < 4; ++it) {
        const int bid = it * 256 + (int)blockIdx.x;
        // ---- wait prefetched x, then convert Xf (f32) -> Xs (bf16) ----
        asm volatile("s_waitcnt vmcnt(0)" ::: "memory");
        __syncthreads();
#pragma unroll
        for (int i = 0; i < 4; ++i) {
            int p   = tid + i * 512;          // float8 index 0..2047
            int tok = p >> 5;
            int col = (p & 31) * 8;
            const float4 lo = *reinterpret_cast<const float4*>(&XfF[p * 8]);
            const float4 hi = *reinterpret_cast<const float4*>(&XfF[p * 8 + 4]);
            bf16x8 w;
            w[0] = (short)f2bf(lo.x); w[1] = (short)f2bf(lo.y);
            w[2] = (short)f2bf(lo.z); w[3] = (short)f2bf(lo.w);
            w[4] = (short)f2bf(hi.x); w[5] = (short)f2bf(hi.y);
            w[6] = (short)f2bf(hi.z); w[7] = (short)f2bf(hi.w);
            *reinterpret_cast<bf16x8*>(&Xs[tok * XS_STRIDE + col]) = w;
        }
        __syncthreads();                      // Xs ready; Xf fully consumed
        // ---- issue async prefetch of next block's x into Xf ----
        if (it < 3) {
            const float* src = x + (size_t)(bid + 256) * 16384;
#pragma unroll
            for (int i = 0; i < 8; ++i) {
                int chunk = wid * 8 + i;
                gload_lds16(src + chunk * 256 + lane * 4, XfF + chunk * 256);
            }
        }

        // ---- merged V / Q^T / K^T projections (one kk loop, 24 MFMA/kk) ----
        // Q^T,K^T: A = W-frag (m=d), B = Xs rows (n=token) -> lane: token=nt*16+l15, d=mt*16+4g+r
        // V:       A = Xs rows (m=token), B = Wv-frag (n=d) -> lane: d=dh*16+l15, token=mi*16+4g+r
        bf16x8 qtf[4], ktf[4], vtf[2][2];
        {
            f32x4 qt[2][4] = {{fz, fz, fz, fz}, {fz, fz, fz, fz}};
            f32x4 kt[2][4] = {{fz, fz, fz, fz}, {fz, fz, fz, fz}};
            f32x4 vac[4][2] = {{fz, fz}, {fz, fz}, {fz, fz}, {fz, fz}};
            __builtin_amdgcn_s_setprio(1);
#pragma unroll
            for (int kk = 0; kk < 8; ++kk) {
                bf16x8 bx[4];
#pragma unroll
                for (int nt = 0; nt < 4; ++nt)
                    bx[nt] = *reinterpret_cast<const bf16x8*>(&Xs[(nt * 16 + l15) * XS_STRIDE + kk * 32 + g * 8]);
                bf16x8 awq[2], awk[2], bv[2];
#pragma unroll
                for (int t = 0; t < 2; ++t) {
                    awq[t] = WFRAG(0, t, kk);
                    awk[t] = WFRAG(1, t, kk);
                    bv[t]  = WFRAG(2, t, kk);
                }
#pragma unroll
                for (int mt = 0; mt < 2; ++mt)
#pragma unroll
                    for (int nt = 0; nt < 4; ++nt) {
                        qt[mt][nt] = mfma_bf16(awq[mt], bx[nt], qt[mt][nt]);
                        kt[mt][nt] = mfma_bf16(awk[mt], bx[nt], kt[mt][nt]);
                    }
#pragma unroll
                for (int mi = 0; mi < 4; ++mi)
#pragma unroll
                    for (int dh = 0; dh < 2; ++dh)
                        vac[mi][dh] = mfma_bf16(bx[mi], bv[dh], vac[mi][dh]);
            }
            __builtin_amdgcn_s_setprio(0);
#pragma unroll
            for (int nt = 0; nt < 4; ++nt) {
                qtf[nt] = pack2(qt[0][nt], qt[1][nt]);
                ktf[nt] = pack2(kt[0][nt], kt[1][nt]);
            }
#pragma unroll
            for (int dh = 0; dh < 2; ++dh) {
                vtf[0][dh] = pack2(vac[0][dh], vac[1][dh]);
                vtf[1][dh] = pack2(vac[2][dh], vac[3][dh]);
            }
        }

        // ---- per q-tile ni: S^T = K Q^T, softmax over k_tok, pa, PV, Os ----
        // st[mi]: lane -> k_tok = mi*16 + 4g + r, q = ni*16 + l15
#pragma unroll
        for (int ni = 0; ni < 4; ++ni) {
            f32x4 st[4];
#pragma unroll
            for (int mi = 0; mi < 4; ++mi)
                st[mi] = mfma_bf16(ktf[mi], qtf[ni], fz);
            float m = st[0][0];
#pragma unroll
            for (int mi = 0; mi < 4; ++mi)
#pragma unroll
                for (int r = 0; r < 4; ++r) m = fmaxf(m, st[mi][r]);
            m = fmaxf(m, __shfl_xor(m, 16));
            m = fmaxf(m, __shfl_xor(m, 32));
            float sum = 0.f;
#pragma unroll
            for (int mi = 0; mi < 4; ++mi)
#pragma unroll
                for (int r = 0; r < 4; ++r) {
                    st[mi][r] = exp2f((st[mi][r] - m) * kC);   // in place
                    sum += st[mi][r];
                }
            sum += __shfl_xor(sum, 16);
            sum += __shfl_xor(sum, 32);
            float inv = 1.0f / sum;
            bf16x8 pa[2];                            // P fragment for THIS q-tile only
#pragma unroll
            for (int kk = 0; kk < 2; ++kk) {
                bf16x8 t;
#pragma unroll
                for (int j = 0; j < 4; ++j) {
                    t[j]     = (short)f2bf(st[2 * kk][j] * inv);
                    t[4 + j] = (short)f2bf(st[2 * kk + 1][j] * inv);
                }
                pa[kk] = t;
            }
            f32x4 oacc[2] = {fz, fz};
#pragma unroll
            for (int kk = 0; kk < 2; ++kk)
#pragma unroll
                for (int dh = 0; dh < 2; ++dh)
                    oacc[dh] = mfma_bf16(pa[kk], vtf[kk][dh], oacc[dh]);
#pragma unroll
            for (int dh = 0; dh < 2; ++dh)
#pragma unroll
                for (int r = 0; r < 4; ++r)
                    Os[(ni * 16 + g * 4 + r) * XS_STRIDE + wid * 32 + dh * 16 + l15] = f2bf(oacc[dh][r]);
        }
        __syncthreads();                      // Os ready for all waves

        // ---- Y = Os @ Wo + bo, f32 store ----
        {
            f32x4 yacc[4][2] = {{fz, fz}, {fz, fz}, {fz, fz}, {fz, fz}};
            __builtin_amdgcn_s_setprio(1);
#pragma unroll
            for (int kk = 0; kk < 8; ++kk) {
                bf16x8 a[4], b[2];
                b[0] = WFRAG(3, 0, kk);
                b[1] = WFRAG(3, 1, kk);
#pragma unroll
                for (int mi = 0; mi < 4; ++mi)
                    a[mi] = *reinterpret_cast<const bf16x8*>(&Os[(mi * 16 + l15) * XS_STRIDE + kk * 32 + g * 8]);
#pragma unroll
                for (int mi = 0; mi < 4; ++mi)
#pragma unroll
                    for (int ni = 0; ni < 2; ++ni)
                        yacc[mi][ni] = mfma_bf16(a[mi], b[ni], yacc[mi][ni]);
            }
            __builtin_amdgcn_s_setprio(0);
            const long long base_tok = (long long)bid * 64;
#pragma unroll
            for (int mi = 0; mi < 4; ++mi) {
#pragma unroll
                for (int ni = 0; ni < 2; ++ni) {
                    int col = wid * 32 + ni * 16 + l15;
                    float bv = bo[col];
#pragma unroll
                    for (int r = 0; r < 4; ++r) {
                        int row = mi * 16 + g * 4 + r;
                        out[(base_tok + row) * 256 + col] = yacc[mi][ni][r] + bv;
                    }
                }
            }
        }
        // loop-top vmcnt(0)+barrier of next iteration orders: out stores done,
        // prefetch DMAs done, all waves' Os reads done before Xs/Os rewrites.
    }
#undef WFRAG
}

extern "C" void kernel_launch(void* const* d_in, const int* in_sizes, int n_in,
                              void* d_out, int out_size, void* d_ws, size_t ws_size,
                              hipStream_t stream) {
    const float* x  = (const float*)d_in[0];
    const float* wq = (const float*)d_in[1];
    const float* wk = (const float*)d_in[2];
    const float* wv = (const float*)d_in[3];
    const float* wo = (const float*)d_in[4];
    const float* bo = (const float*)d_in[5];
    unsigned short* wt = (unsigned short*)d_ws;      // 4 * 256*256 bf16 = 512 KiB
    float* out = (float*)d_out;                      // f32 output

    prep_weights<<<128, 256, 0, stream>>>(wq, wk, wv, wo, wt);
    win_attn<<<256, 512, 0, stream>>>(x, wt, bo, out);
}

// Round 13
// 70.256 us; speedup vs baseline: 2.2556x; 1.4389x over previous
//
#include <hip/hip_runtime.h>
#include <hip/hip_bf16.h>

typedef short bf16x8 __attribute__((ext_vector_type(8)));
typedef float f32x4  __attribute__((ext_vector_type(4)));

__device__ __forceinline__ unsigned short f2bf(float f) {
    union { __hip_bfloat16 b; unsigned short u; } v;
    v.b = __hip_bfloat16(f);          // native RNE cvt (pairs into v_cvt_pk_bf16_f32)
    return v.u;
}

// MFMA pinned to arch VGPRs via inline asm -> zero AGPRs -> the full
// __launch_bounds__ budget is arch registers (r4/r6/r7/r10: the builtin path
// splits the unified file ~50/50 and spills).
// s_nop 1 INSIDE the asm: 2 wait states covering compiler-inserted VALU copies
// (tied-operand v_movs) immediately preceding the MFMA — the backend hazard
// recognizer cannot see into asm, so we carry our own VALU->MFMA protection
// (r12 failed exactly here: absmax 4.09 from unprotected fz->acc copies).
__device__ __forceinline__ f32x4 mfma_bf16(bf16x8 a, bf16x8 b, f32x4 c) {
    asm volatile("s_nop 1\n\tv_mfma_f32_16x16x32_bf16 %0, %1, %2, %0"
                 : "+v"(c) : "v"(a), "v"(b));
    return c;
}

// Cluster-boundary fences. mfma_fence: 16 wait states >= 4-pass MFMA write ->
// VALU read requirement; sched_barrier(0) pins so no VALU read hoists into the
// MFMA cluster from below.
__device__ __forceinline__ void mfma_fence() {          // MFMA write -> VALU read
    __builtin_amdgcn_sched_barrier(0);
    asm volatile("s_nop 7\n\ts_nop 7");
    __builtin_amdgcn_sched_barrier(0);
}
__device__ __forceinline__ void valu_mfma_fence() {     // VALU write -> MFMA read
    __builtin_amdgcn_sched_barrier(0);
    asm volatile("s_nop 1");
    __builtin_amdgcn_sched_barrier(0);
}

// pack two f32x4 acc tiles (m-tile 0, m-tile 1) into one bf16 fragment under
// the shared k-bijection pi(g,j) = {4g+j | j<4} u {16+4g+(j-4) | j>=4}
__device__ __forceinline__ bf16x8 pack2(f32x4 lo, f32x4 hi) {
    bf16x8 r;
    r[0] = (short)f2bf(lo[0]); r[1] = (short)f2bf(lo[1]);
    r[2] = (short)f2bf(lo[2]); r[3] = (short)f2bf(lo[3]);
    r[4] = (short)f2bf(hi[0]); r[5] = (short)f2bf(hi[1]);
    r[6] = (short)f2bf(hi[2]); r[7] = (short)f2bf(hi[3]);
    return r;
}

// ---------------- prep: weights -> MFMA-fragment-linear bf16 layout ----------------
// slot s = (((mat*8 + h)*2 + t)*8 + kk)*64 + lane ; each slot = 8 bf16 (16 B).
// content: W[k][n] for n = h*32 + t*16 + (lane&15), k = kk*32 + (lane>>4)*8 + j.
__global__ __launch_bounds__(256) void prep_weights(
    const float* __restrict__ wq, const float* __restrict__ wk,
    const float* __restrict__ wv, const float* __restrict__ wo,
    unsigned short* __restrict__ wt)
{
    const int s = blockIdx.x * 256 + threadIdx.x;   // 0..32767
    const int mat  = s >> 13;
    const int h    = (s >> 10) & 7;
    const int t    = (s >> 9) & 1;
    const int kk   = (s >> 6) & 7;
    const int lane = s & 63;
    const int l15  = lane & 15;
    const int g    = lane >> 4;
    const float* src = (mat == 0) ? wq : (mat == 1) ? wk : (mat == 2) ? wv : wo;
    const int n  = h * 32 + t * 16 + l15;
    const int k0 = kk * 32 + g * 8;
    unsigned short* dst = wt + (size_t)s * 8;
#pragma unroll
    for (int j = 0; j < 8; ++j)
        dst[j] = f2bf(src[(k0 + j) * 256 + n]);
}

// ---------------- fused window attention, register-resident attention ----------------
// grid = 1024 (= 16 b * 64 h), block = 512 (8 waves). Each WG owns 64 tokens.
// wave w = head w. SEQUENTIAL projections (V per-d-half -> Q^T -> K^T) keep arch
// peak ~100 regs; asm-VGPR MFMA -> zero AGPRs -> (512,4)'s 128-reg budget all
// arch -> no spill -> 4 waves/SIMD -> 2 WGs/CU. Attention register-resident.
#define XS_STRIDE 264   // 256 + 8 pad shorts

__global__ __launch_bounds__(512, 4) void win_attn(
    const float* __restrict__ x,
    const unsigned short* __restrict__ wt,   // fragment-linear weights (512 KiB)
    const float* __restrict__ bo,
    float* __restrict__ out)                 // f32 output
{
    __shared__ unsigned short lds[33792];    // 66 KiB
    unsigned short* Xs = lds;                // [64][264]
    unsigned short* Os = lds + 16896;        // [64][264]

    const int tid  = threadIdx.x;
    const int wid  = tid >> 6;               // 0..7 (= head)
    const int lane = tid & 63;
    const int l15  = lane & 15;
    const int g    = lane >> 4;              // 0..3

    const bf16x8* WF = reinterpret_cast<const bf16x8*>(wt);
    // fragment index: (((mat*8 + wid)*2 + t)*8 + kk)*64 + lane
    const int wbase = (wid * 2) * 8 * 64 + lane;
#define WFRAG(mat, t, kk) WF[(mat) * 8192 + wbase + ((t) * 8 + (kk)) * 64]

    const long long base_tok = (long long)blockIdx.x * 64;
    const float* xblk = x + base_tok * 256;

    const f32x4 fz = {0.f, 0.f, 0.f, 0.f};

    // ---- phase 0: stage x row-block as bf16 in LDS ----
#pragma unroll
    for (int i = 0; i < 8; ++i) {
        int p   = tid + i * 512;             // float4 index, 0..4095
        int tok = p >> 6;
        int col = (p & 63) * 4;
        float4 v = reinterpret_cast<const float4*>(xblk)[p];
        ushort4 h;
        h.x = f2bf(v.x); h.y = f2bf(v.y); h.z = f2bf(v.z); h.w = f2bf(v.w);
        *reinterpret_cast<ushort4*>(&Xs[tok * XS_STRIDE + col]) = h;
    }
    __syncthreads();

    // ---- phase 1: V = X Wv, one d-half at a time -> PV B-frags ----
    // lane: d = dh*16 + l15, token = mi*16 + 4g + r
    bf16x8 vtf[2][2];                            // [k-half][d-half], 16 regs
#pragma unroll
    for (int dh = 0; dh < 2; ++dh) {
        f32x4 vac[4] = {fz, fz, fz, fz};
        valu_mfma_fence();
#pragma unroll
        for (int kk = 0; kk < 8; ++kk) {
            bf16x8 bv = WFRAG(2, dh, kk);
#pragma unroll
            for (int mi = 0; mi < 4; ++mi) {
                bf16x8 a = *reinterpret_cast<const bf16x8*>(&Xs[(mi * 16 + l15) * XS_STRIDE + kk * 32 + g * 8]);
                vac[mi] = mfma_bf16(a, bv, vac[mi]);
            }
        }
        mfma_fence();
        vtf[0][dh] = pack2(vac[0], vac[1]);
        vtf[1][dh] = pack2(vac[2], vac[3]);
    }

    // ---- phase 2: Q^T = mfma(A = Wq-frag (m=d), B = Xs rows (n=token)) ----
    // lane: token = nt*16 + l15, d = mt*16 + 4g + r
    bf16x8 qtf[4];
    {
        f32x4 qt[2][4] = {{fz, fz, fz, fz}, {fz, fz, fz, fz}};
        valu_mfma_fence();
#pragma unroll
        for (int kk = 0; kk < 8; ++kk) {
            bf16x8 aw[2], bx[4];
            aw[0] = WFRAG(0, 0, kk);
            aw[1] = WFRAG(0, 1, kk);
#pragma unroll
            for (int nt = 0; nt < 4; ++nt)
                bx[nt] = *reinterpret_cast<const bf16x8*>(&Xs[(nt * 16 + l15) * XS_STRIDE + kk * 32 + g * 8]);
#pragma unroll
            for (int mt = 0; mt < 2; ++mt)
#pragma unroll
                for (int nt = 0; nt < 4; ++nt)
                    qt[mt][nt] = mfma_bf16(aw[mt], bx[nt], qt[mt][nt]);
        }
        mfma_fence();
#pragma unroll
        for (int nt = 0; nt < 4; ++nt) qtf[nt] = pack2(qt[0][nt], qt[1][nt]);
    }

    // ---- phase 3: K^T, same structure ----
    bf16x8 ktf[4];
    {
        f32x4 kt[2][4] = {{fz, fz, fz, fz}, {fz, fz, fz, fz}};
        valu_mfma_fence();
#pragma unroll
        for (int kk = 0; kk < 8; ++kk) {
            bf16x8 aw[2], bx[4];
            aw[0] = WFRAG(1, 0, kk);
            aw[1] = WFRAG(1, 1, kk);
#pragma unroll
            for (int nt = 0; nt < 4; ++nt)
                bx[nt] = *reinterpret_cast<const bf16x8*>(&Xs[(nt * 16 + l15) * XS_STRIDE + kk * 32 + g * 8]);
#pragma unroll
            for (int mt = 0; mt < 2; ++mt)
#pragma unroll
                for (int nt = 0; nt < 4; ++nt)
                    kt[mt][nt] = mfma_bf16(aw[mt], bx[nt], kt[mt][nt]);
        }
        mfma_fence();
#pragma unroll
        for (int nt = 0; nt < 4; ++nt) ktf[nt] = pack2(kt[0][nt], kt[1][nt]);
    }

    // ---- phase 4: per q-tile ni: S^T = K Q^T, softmax over k_tok, pa, PV, Os ----
    // st[mi]: lane -> k_tok = mi*16 + 4g + r, q = ni*16 + l15
    constexpr float kC = 0.25501817419392105f;  // (1/sqrt(32)) * log2(e)
#pragma unroll
    for (int ni = 0; ni < 4; ++ni) {
        f32x4 st[4];
        valu_mfma_fence();
#pragma unroll
        for (int mi = 0; mi < 4; ++mi)
            st[mi] = mfma_bf16(ktf[mi], qtf[ni], fz);
        mfma_fence();
        float m = st[0][0];
#pragma unroll
        for (int mi = 0; mi < 4; ++mi)
#pragma unroll
            for (int r = 0; r < 4; ++r) m = fmaxf(m, st[mi][r]);
        m = fmaxf(m, __shfl_xor(m, 16));
        m = fmaxf(m, __shfl_xor(m, 32));
        float sum = 0.f;
#pragma unroll
        for (int mi = 0; mi < 4; ++mi)
#pragma unroll
            for (int r = 0; r < 4; ++r) {
                st[mi][r] = exp2f((st[mi][r] - m) * kC);   // in place
                sum += st[mi][r];
            }
        sum += __shfl_xor(sum, 16);
        sum += __shfl_xor(sum, 32);
        float inv = 1.0f / sum;
        bf16x8 pa[2];                            // P fragment for THIS q-tile only
#pragma unroll
        for (int kk = 0; kk < 2; ++kk) {
            bf16x8 t;
#pragma unroll
            for (int j = 0; j < 4; ++j) {
                t[j]     = (short)f2bf(st[2 * kk][j] * inv);
                t[4 + j] = (short)f2bf(st[2 * kk + 1][j] * inv);
            }
            pa[kk] = t;
        }
        f32x4 oacc[2] = {fz, fz};
        valu_mfma_fence();
#pragma unroll
        for (int kk = 0; kk < 2; ++kk)
#pragma unroll
            for (int dh = 0; dh < 2; ++dh)
                oacc[dh] = mfma_bf16(pa[kk], vtf[kk][dh], oacc[dh]);
        mfma_fence();
#pragma unroll
        for (int dh = 0; dh < 2; ++dh)
#pragma unroll
            for (int r = 0; r < 4; ++r)
                Os[(ni * 16 + g * 4 + r) * XS_STRIDE + wid * 32 + dh * 16 + l15] = f2bf(oacc[dh][r]);
    }
    __syncthreads();

    // ---- phase 5: Y = Os @ Wo + bo, f32 store ----
    {
        f32x4 yacc[4][2] = {{fz, fz}, {fz, fz}, {fz, fz}, {fz, fz}};
        valu_mfma_fence();
#pragma unroll
        for (int kk = 0; kk < 8; ++kk) {
            bf16x8 a[4], b[2];
            b[0] = WFRAG(3, 0, kk);
            b[1] = WFRAG(3, 1, kk);
#pragma unroll
            for (int mi = 0; mi < 4; ++mi)
                a[mi] = *reinterpret_cast<const bf16x8*>(&Os[(mi * 16 + l15) * XS_STRIDE + kk * 32 + g * 8]);
#pragma unroll
            for (int mi = 0; mi < 4; ++mi)
#pragma unroll
                for (int ni = 0; ni < 2; ++ni)
                    yacc[mi][ni] = mfma_bf16(a[mi], b[ni], yacc[mi][ni]);
        }
        mfma_fence();
#pragma unroll
        for (int mi = 0; mi < 4; ++mi) {
#pragma unroll
            for (int ni = 0; ni < 2; ++ni) {
                int col = wid * 32 + ni * 16 + l15;
                float bv = bo[col];
#pragma unroll
                for (int r = 0; r < 4; ++r) {
                    int row = mi * 16 + g * 4 + r;
                    out[(base_tok + row) * 256 + col] = yacc[mi][ni][r] + bv;
                }
            }
        }
    }
#undef WFRAG
}

extern "C" void kernel_launch(void* const* d_in, const int* in_sizes, int n_in,
                              void* d_out, int out_size, void* d_ws, size_t ws_size,
                              hipStream_t stream) {
    const float* x  = (const float*)d_in[0];
    const float* wq = (const float*)d_in[1];
    const float* wk = (const float*)d_in[2];
    const float* wv = (const float*)d_in[3];
    const float* wo = (const float*)d_in[4];
    const float* bo = (const float*)d_in[5];
    unsigned short* wt = (unsigned short*)d_ws;      // 4 * 256*256 bf16 = 512 KiB
    float* out = (float*)d_out;                      // f32 output

    prep_weights<<<128, 256, 0, stream>>>(wq, wk, wv, wo, wt);
    win_attn<<<1024, 512, 0, stream>>>(x, wt, bo, out);
}

// Round 15
// 65.858 us; speedup vs baseline: 2.4063x; 1.0668x over previous
//
#include <hip/hip_runtime.h>
#include <hip/hip_bf16.h>

typedef short bf16x8 __attribute__((ext_vector_type(8)));
typedef float f32x4  __attribute__((ext_vector_type(4)));

__device__ __forceinline__ unsigned short f2bf(float f) {
    union { __hip_bfloat16 b; unsigned short u; } v;
    v.b = __hip_bfloat16(f);          // native RNE cvt (pairs into v_cvt_pk_bf16_f32)
    return v.u;
}

// MFMA pinned to arch VGPRs via inline asm -> zero AGPRs -> the full
// __launch_bounds__ budget is arch registers (r13 confirmed: 56 arch, 0 agpr,
// no spill, 39% occupancy). VOLATILE is load-bearing: r14 dropped it and the
// scheduler sank MFMAs past the hazard fences -> NaN. ILP therefore comes from
// MANUAL program-order pipelining (loads for kk+1 issued before kk's cluster),
// not from scheduler freedom.
// s_nop 1 embedded: 2 wait states covering whatever VALU write the compiler
// parks right before the MFMA (r12 failure mode; backend can't see into asm).
__device__ __forceinline__ f32x4 mfma_bf16(bf16x8 a, bf16x8 b, f32x4 c) {
    asm volatile("s_nop 1\n\tv_mfma_f32_16x16x32_bf16 %0, %1, %2, %0"
                 : "+v"(c) : "v"(a), "v"(b));
    return c;
}

// Cluster-boundary fence: 16 wait states >= MFMA-write -> VALU-read hazard.
// sched_barrier(0) pins everything (r13-proven correct).
__device__ __forceinline__ void mfma_fence() {
    __builtin_amdgcn_sched_barrier(0);
    asm volatile("s_nop 7\n\ts_nop 7");
    __builtin_amdgcn_sched_barrier(0);
}

// pack two f32x4 acc tiles (m-tile 0, m-tile 1) into one bf16 fragment under
// the shared k-bijection pi(g,j) = {4g+j | j<4} u {16+4g+(j-4) | j>=4}
__device__ __forceinline__ bf16x8 pack2(f32x4 lo, f32x4 hi) {
    bf16x8 r;
    r[0] = (short)f2bf(lo[0]); r[1] = (short)f2bf(lo[1]);
    r[2] = (short)f2bf(lo[2]); r[3] = (short)f2bf(lo[3]);
    r[4] = (short)f2bf(hi[0]); r[5] = (short)f2bf(hi[1]);
    r[6] = (short)f2bf(hi[2]); r[7] = (short)f2bf(hi[3]);
    return r;
}

// ---------------- prep: weights -> MFMA-fragment-linear bf16 layout ----------------
// slot s = (((mat*8 + h)*2 + t)*8 + kk)*64 + lane ; each slot = 8 bf16 (16 B).
// content: W[k][n] for n = h*32 + t*16 + (lane&15), k = kk*32 + (lane>>4)*8 + j.
__global__ __launch_bounds__(256) void prep_weights(
    const float* __restrict__ wq, const float* __restrict__ wk,
    const float* __restrict__ wv, const float* __restrict__ wo,
    unsigned short* __restrict__ wt)
{
    const int s = blockIdx.x * 256 + threadIdx.x;   // 0..32767
    const int mat  = s >> 13;
    const int h    = (s >> 10) & 7;
    const int t    = (s >> 9) & 1;
    const int kk   = (s >> 6) & 7;
    const int lane = s & 63;
    const int l15  = lane & 15;
    const int g    = lane >> 4;
    const float* src = (mat == 0) ? wq : (mat == 1) ? wk : (mat == 2) ? wv : wo;
    const int n  = h * 32 + t * 16 + l15;
    const int k0 = kk * 32 + g * 8;
    unsigned short* dst = wt + (size_t)s * 8;
#pragma unroll
    for (int j = 0; j < 8; ++j)
        dst[j] = f2bf(src[(k0 + j) * 256 + n]);
}

// ---------------- fused window attention, register-resident attention ----------------
// grid = 1024 (= 16 b * 64 h), block = 512 (8 waves). Each WG owns 64 tokens.
// wave w = head w. SEQUENTIAL projections (V per-d-half -> Q^T -> K^T), zero
// AGPRs -> (512,4) 128-reg arch budget -> 2 WGs/CU. W-fragment loads are
// software-pipelined 1-deep IN PROGRAM ORDER (kk+1's loads before kk's volatile
// MFMA cluster) so their L2 latency hides under the MFMAs.
#define XS_STRIDE 264   // 256 + 8 pad shorts

__global__ __launch_bounds__(512, 4) void win_attn(
    const float* __restrict__ x,
    const unsigned short* __restrict__ wt,   // fragment-linear weights (512 KiB)
    const float* __restrict__ bo,
    float* __restrict__ out)                 // f32 output
{
    __shared__ unsigned short lds[33792];    // 66 KiB
    unsigned short* Xs = lds;                // [64][264]
    unsigned short* Os = lds + 16896;        // [64][264]

    const int tid  = threadIdx.x;
    const int wid  = tid >> 6;               // 0..7 (= head)
    const int lane = tid & 63;
    const int l15  = lane & 15;
    const int g    = lane >> 4;              // 0..3

    const bf16x8* WF = reinterpret_cast<const bf16x8*>(wt);
    // fragment index: (((mat*8 + wid)*2 + t)*8 + kk)*64 + lane
    const int wbase = (wid * 2) * 8 * 64 + lane;
#define WFRAG(mat, t, kk) WF[(mat) * 8192 + wbase + ((t) * 8 + (kk)) * 64]

    const long long base_tok = (long long)blockIdx.x * 64;
    const float* xblk = x + base_tok * 256;

    const f32x4 fz = {0.f, 0.f, 0.f, 0.f};

    // ---- phase 0: stage x row-block as bf16 in LDS ----
#pragma unroll
    for (int i = 0; i < 8; ++i) {
        int p   = tid + i * 512;             // float4 index, 0..4095
        int tok = p >> 6;
        int col = (p & 63) * 4;
        float4 v = reinterpret_cast<const float4*>(xblk)[p];
        ushort4 h;
        h.x = f2bf(v.x); h.y = f2bf(v.y); h.z = f2bf(v.z); h.w = f2bf(v.w);
        *reinterpret_cast<ushort4*>(&Xs[tok * XS_STRIDE + col]) = h;
    }
    __syncthreads();

    // ---- phase 1: V = X Wv, one d-half at a time -> PV B-frags ----
    // lane: d = dh*16 + l15, token = mi*16 + 4g + r
    bf16x8 vtf[2][2];                            // [k-half][d-half]
#pragma unroll
    for (int dh = 0; dh < 2; ++dh) {
        f32x4 vac[4] = {fz, fz, fz, fz};
        bf16x8 bvc = WFRAG(2, dh, 0);            // pipeline prologue
#pragma unroll
        for (int kk = 0; kk < 8; ++kk) {
            bf16x8 bvn = bvc;
            if (kk < 7) bvn = WFRAG(2, dh, kk + 1);   // issue next BEFORE cluster
#pragma unroll
            for (int mi = 0; mi < 4; ++mi) {
                bf16x8 a = *reinterpret_cast<const bf16x8*>(&Xs[(mi * 16 + l15) * XS_STRIDE + kk * 32 + g * 8]);
                vac[mi] = mfma_bf16(a, bvc, vac[mi]);
            }
            bvc = bvn;
        }
        mfma_fence();
        vtf[0][dh] = pack2(vac[0], vac[1]);
        vtf[1][dh] = pack2(vac[2], vac[3]);
    }

    // ---- phase 2: Q^T = mfma(A = Wq-frag (m=d), B = Xs rows (n=token)) ----
    // lane: token = nt*16 + l15, d = mt*16 + 4g + r
    bf16x8 qtf[4];
    {
        f32x4 qt[2][4] = {{fz, fz, fz, fz}, {fz, fz, fz, fz}};
        bf16x8 awc0 = WFRAG(0, 0, 0), awc1 = WFRAG(0, 1, 0);
#pragma unroll
        for (int kk = 0; kk < 8; ++kk) {
            bf16x8 awn0 = awc0, awn1 = awc1;
            if (kk < 7) { awn0 = WFRAG(0, 0, kk + 1); awn1 = WFRAG(0, 1, kk + 1); }
            bf16x8 bx[4];
#pragma unroll
            for (int nt = 0; nt < 4; ++nt)
                bx[nt] = *reinterpret_cast<const bf16x8*>(&Xs[(nt * 16 + l15) * XS_STRIDE + kk * 32 + g * 8]);
#pragma unroll
            for (int nt = 0; nt < 4; ++nt) {
                qt[0][nt] = mfma_bf16(awc0, bx[nt], qt[0][nt]);
                qt[1][nt] = mfma_bf16(awc1, bx[nt], qt[1][nt]);
            }
            awc0 = awn0; awc1 = awn1;
        }
        mfma_fence();
#pragma unroll
        for (int nt = 0; nt < 4; ++nt) qtf[nt] = pack2(qt[0][nt], qt[1][nt]);
    }

    // ---- phase 3: K^T, same structure ----
    bf16x8 ktf[4];
    {
        f32x4 kt[2][4] = {{fz, fz, fz, fz}, {fz, fz, fz, fz}};
        bf16x8 awc0 = WFRAG(1, 0, 0), awc1 = WFRAG(1, 1, 0);
#pragma unroll
        for (int kk = 0; kk < 8; ++kk) {
            bf16x8 awn0 = awc0, awn1 = awc1;
            if (kk < 7) { awn0 = WFRAG(1, 0, kk + 1); awn1 = WFRAG(1, 1, kk + 1); }
            bf16x8 bx[4];
#pragma unroll
            for (int nt = 0; nt < 4; ++nt)
                bx[nt] = *reinterpret_cast<const bf16x8*>(&Xs[(nt * 16 + l15) * XS_STRIDE + kk * 32 + g * 8]);
#pragma unroll
            for (int nt = 0; nt < 4; ++nt) {
                kt[0][nt] = mfma_bf16(awc0, bx[nt], kt[0][nt]);
                kt[1][nt] = mfma_bf16(awc1, bx[nt], kt[1][nt]);
            }
            awc0 = awn0; awc1 = awn1;
        }
        mfma_fence();
#pragma unroll
        for (int nt = 0; nt < 4; ++nt) ktf[nt] = pack2(kt[0][nt], kt[1][nt]);
    }

    // ---- phase 4: per q-tile ni: S^T = K Q^T, softmax over k_tok, pa, PV, Os ----
    // st[mi]: lane -> k_tok = mi*16 + 4g + r, q = ni*16 + l15
    constexpr float kC = 0.25501817419392105f;  // (1/sqrt(32)) * log2(e)
#pragma unroll
    for (int ni = 0; ni < 4; ++ni) {
        f32x4 st[4];
#pragma unroll
        for (int mi = 0; mi < 4; ++mi)
            st[mi] = mfma_bf16(ktf[mi], qtf[ni], fz);
        mfma_fence();
        float m = st[0][0];
#pragma unroll
        for (int mi = 0; mi < 4; ++mi)
#pragma unroll
            for (int r = 0; r < 4; ++r) m = fmaxf(m, st[mi][r]);
        m = fmaxf(m, __shfl_xor(m, 16));
        m = fmaxf(m, __shfl_xor(m, 32));
        float sum = 0.f;
#pragma unroll
        for (int mi = 0; mi < 4; ++mi)
#pragma unroll
            for (int r = 0; r < 4; ++r) {
                st[mi][r] = exp2f((st[mi][r] - m) * kC);   // in place
                sum += st[mi][r];
            }
        sum += __shfl_xor(sum, 16);
        sum += __shfl_xor(sum, 32);
        float inv = 1.0f / sum;
        bf16x8 pa[2];                            // P fragment for THIS q-tile only
#pragma unroll
        for (int kk = 0; kk < 2; ++kk) {
            bf16x8 t;
#pragma unroll
            for (int j = 0; j < 4; ++j) {
                t[j]     = (short)f2bf(st[2 * kk][j] * inv);
                t[4 + j] = (short)f2bf(st[2 * kk + 1][j] * inv);
            }
            pa[kk] = t;
        }
        f32x4 oacc[2] = {fz, fz};
#pragma unroll
        for (int kk = 0; kk < 2; ++kk)
#pragma unroll
            for (int dh = 0; dh < 2; ++dh)
                oacc[dh] = mfma_bf16(pa[kk], vtf[kk][dh], oacc[dh]);
        mfma_fence();
#pragma unroll
        for (int dh = 0; dh < 2; ++dh)
#pragma unroll
            for (int r = 0; r < 4; ++r)
                Os[(ni * 16 + g * 4 + r) * XS_STRIDE + wid * 32 + dh * 16 + l15] = f2bf(oacc[dh][r]);
    }
    __syncthreads();

    // ---- phase 5: Y = Os @ Wo + bo, f32 store ----
    {
        f32x4 yacc[4][2] = {{fz, fz}, {fz, fz}, {fz, fz}, {fz, fz}};
        bf16x8 bc0 = WFRAG(3, 0, 0), bc1 = WFRAG(3, 1, 0);
#pragma unroll
        for (int kk = 0; kk < 8; ++kk) {
            bf16x8 bn0 = bc0, bn1 = bc1;
            if (kk < 7) { bn0 = WFRAG(3, 0, kk + 1); bn1 = WFRAG(3, 1, kk + 1); }
            bf16x8 a[4];
#pragma unroll
            for (int mi = 0; mi < 4; ++mi)
                a[mi] = *reinterpret_cast<const bf16x8*>(&Os[(mi * 16 + l15) * XS_STRIDE + kk * 32 + g * 8]);
#pragma unroll
            for (int mi = 0; mi < 4; ++mi) {
                yacc[mi][0] = mfma_bf16(a[mi], bc0, yacc[mi][0]);
                yacc[mi][1] = mfma_bf16(a[mi], bc1, yacc[mi][1]);
            }
            bc0 = bn0; bc1 = bn1;
        }
        mfma_fence();
#pragma unroll
        for (int mi = 0; mi < 4; ++mi) {
#pragma unroll
            for (int ni = 0; ni < 2; ++ni) {
                int col = wid * 32 + ni * 16 + l15;
                float bv = bo[col];
#pragma unroll
                for (int r = 0; r < 4; ++r) {
                    int row = mi * 16 + g * 4 + r;
                    out[(base_tok + row) * 256 + col] = yacc[mi][ni][r] + bv;
                }
            }
        }
    }
#undef WFRAG
}

extern "C" void kernel_launch(void* const* d_in, const int* in_sizes, int n_in,
                              void* d_out, int out_size, void* d_ws, size_t ws_size,
                              hipStream_t stream) {
    const float* x  = (const float*)d_in[0];
    const float* wq = (const float*)d_in[1];
    const float* wk = (const float*)d_in[2];
    const float* wv = (const float*)d_in[3];
    const float* wo = (const float*)d_in[4];
    const float* bo = (const float*)d_in[5];
    unsigned short* wt = (unsigned short*)d_ws;      // 4 * 256*256 bf16 = 512 KiB
    float* out = (float*)d_out;                      // f32 output

    prep_weights<<<128, 256, 0, stream>>>(wq, wk, wv, wo, wt);
    win_attn<<<1024, 512, 0, stream>>>(x, wt, bo, out);
}